// Round 8
// baseline (47.873 us; speedup 1.0000x reference)
//
#include <hip/hip_runtime.h>

// Problem constants (from reference)
#define B_    16
#define N_    25200
#define NC_   80
#define NM_   32
#define NDET_ 100
#define H_    160
#define W_    160
#define HW_   (H_ * W_)
#define XDIM_ (5 + NC_ + NM_)   // 117
#define COEF_OFF_ (5 + NC_)     // 85

// Output layout (flat f32):
#define OFF_BOXES_   16
#define OFF_SCORES_  6416
#define OFF_CLASSES_ 8016
#define OFF_MASKS_   9616

#define ODET_ (NDET_ / 4)       // 25 detections per wave

typedef float f32x2 __attribute__((ext_vector_type(2)));
typedef float f32x4 __attribute__((ext_vector_type(4)));

// Block = 4 waves; each wave owns 128 pixels (2 px/thread, dwordx2 memops)
// x 25 detections. Grid (HW/128 = 200 tiles, B = 16) = 3200 blocks = 12800 waves
// (50 waves/CU offered -> full residency). Per-detection data on the scalar pipe.
__global__ __launch_bounds__(256) void mask_kernel(
    const float* __restrict__ x0,
    const float* __restrict__ proto,
    const int*   __restrict__ num_det,
    const float* __restrict__ det_boxes,
    const float* __restrict__ det_scores,
    const int*   __restrict__ det_classes,
    const int*   __restrict__ det_indices,
    float* __restrict__ out)
{
    const int b    = blockIdx.y;
    const int tile = blockIdx.x;
    const int tid  = threadIdx.x;
    const int lane = tid & 63;
    const int wave = __builtin_amdgcn_readfirstlane(tid >> 6);

    // Fused head outputs (tile-0 block of each batch writes the small outputs).
    if (tile == 0) {
        if (tid == 0) out[b] = (float)num_det[b];
        for (int i = tid; i < NDET_ * 4; i += 256)
            out[OFF_BOXES_ + b * NDET_ * 4 + i] = det_boxes[b * NDET_ * 4 + i];
        for (int i = tid; i < NDET_; i += 256) {
            out[OFF_SCORES_  + b * NDET_ + i] = det_scores[b * NDET_ + i];
            out[OFF_CLASSES_ + b * NDET_ + i] = (float)det_classes[b * NDET_ + i];
        }
    }

    // Two adjacent pixels per thread; p0 even and rows start even -> same row.
    const int p0 = tile * 128 + lane * 2;
    const float cf  = (float)(p0 / W_);
    const float rf0 = (float)(p0 % W_);
    const float rf1 = rf0 + 1.0f;

    // This wave's proto columns (32 x float2) in registers.
    const float* __restrict__ pp = proto + (size_t)b * NM_ * HW_ + p0;
    f32x2 pr[NM_];
#pragma unroll
    for (int m = 0; m < NM_; ++m)
        pr[m] = *(const f32x2*)(pp + (size_t)m * HW_);

    const int o0 = wave * ODET_;
    const f32x4* __restrict__ sbox = (const f32x4*)det_boxes + b * NDET_ + o0;
    const int*   __restrict__ dind = det_indices + b * NDET_ + o0;

    float* __restrict__ outp =
        out + OFF_MASKS_ + ((size_t)b * NDET_ + o0) * HW_ + p0;

    for (int i = 0; i < ODET_; ++i) {
        const f32x4 bx = sbox[i];                     // uniform -> s_load_dwordx4
        const float x1 = bx.x * 0.25f, y1 = bx.y * 0.25f;
        const float x2 = bx.z * 0.25f, y2 = bx.w * 0.25f;
        const bool iny = (cf >= y1) & (cf < y2);
        const bool in0 = iny & (rf0 >= x1) & (rf0 < x2);
        const bool in1 = iny & (rf1 >= x1) & (rf1 < x2);
        f32x2 v = {0.0f, 0.0f};
        if (__ballot(in0 | in1) != 0) {
            const int idx = __builtin_amdgcn_readfirstlane(dind[i]);
            const float* __restrict__ cfp =
                x0 + ((size_t)b * N_ + idx) * XDIM_ + COEF_OFF_;
            f32x2 acc = {0.0f, 0.0f};
#pragma unroll
            for (int m = 0; m < NM_; ++m) acc += cfp[m] * pr[m];
            const float s0 = 1.0f / (1.0f + __expf(-acc.x));
            const float s1 = 1.0f / (1.0f + __expf(-acc.y));
            v.x = in0 ? s0 : 0.0f;
            v.y = in1 ? s1 : 0.0f;
        }
        *(f32x2*)(outp + (size_t)i * HW_) = v;
    }
}

extern "C" void kernel_launch(void* const* d_in, const int* in_sizes, int n_in,
                              void* d_out, int out_size, void* d_ws, size_t ws_size,
                              hipStream_t stream)
{
    const float* x0          = (const float*)d_in[0];
    const float* proto       = (const float*)d_in[1];
    const int*   num_det     = (const int*)  d_in[2];
    const float* det_boxes   = (const float*)d_in[3];
    const float* det_scores  = (const float*)d_in[4];
    const int*   det_classes = (const int*)  d_in[5];
    const int*   det_indices = (const int*)  d_in[6];
    float* out = (float*)d_out;

    dim3 grid(HW_ / 128, B_);
    mask_kernel<<<grid, 256, 0, stream>>>(
        x0, proto, num_det, det_boxes, det_scores, det_classes, det_indices, out);
}

// Round 9
// 39.436 us; speedup vs baseline: 1.2139x; 1.2139x over previous
//
#include <hip/hip_runtime.h>

// Problem constants (from reference)
#define B_    16
#define N_    25200
#define NC_   80
#define NM_   32
#define NDET_ 100
#define H_    160
#define W_    160
#define HW_   (H_ * W_)
#define XDIM_ (5 + NC_ + NM_)   // 117
#define COEF_OFF_ (5 + NC_)     // 85

// Output layout (flat f32):
#define OFF_BOXES_   16
#define OFF_SCORES_  6416
#define OFF_CLASSES_ 8016
#define OFF_MASKS_   9616

#define ODET_ (NDET_ / 4)       // 25 detections per wave

typedef float f32x4 __attribute__((ext_vector_type(4)));

// R7 champion restored. Block = 4 waves; each wave owns 64 pixels x 25 detections.
// Grid (HW/64 = 400 tiles, B = 16) = 6400 blocks = 25600 waves. 1 px/thread is
// deliberate: wave64 dword store = 256 B = 1 transaction; wider vectors halve
// TLP without reducing TCC work (R8: 2px/thread regressed 39.2->47.9; R2: 4px
// regressed similarly). Per-detection data (box, index, coefs) is wave-uniform
// -> scalar-pipe s_loads. Plain loads/stores (nt hints regress: R5). Head
// outputs fused into tile-0 blocks (prep-pass fusion won 49.2->45.5: R6).
__global__ __launch_bounds__(256) void mask_kernel(
    const float* __restrict__ x0,
    const float* __restrict__ proto,
    const int*   __restrict__ num_det,
    const float* __restrict__ det_boxes,
    const float* __restrict__ det_scores,
    const int*   __restrict__ det_classes,
    const int*   __restrict__ det_indices,
    float* __restrict__ out)
{
    const int b    = blockIdx.y;
    const int tile = blockIdx.x;
    const int tid  = threadIdx.x;
    const int lane = tid & 63;
    const int wave = __builtin_amdgcn_readfirstlane(tid >> 6);

    // Fused head outputs (tile-0 block of each batch writes the small outputs).
    if (tile == 0) {
        if (tid == 0) out[b] = (float)num_det[b];
        for (int i = tid; i < NDET_ * 4; i += 256)
            out[OFF_BOXES_ + b * NDET_ * 4 + i] = det_boxes[b * NDET_ * 4 + i];
        for (int i = tid; i < NDET_; i += 256) {
            out[OFF_SCORES_  + b * NDET_ + i] = det_scores[b * NDET_ + i];
            out[OFF_CLASSES_ + b * NDET_ + i] = (float)det_classes[b * NDET_ + i];
        }
    }

    const int p = tile * 64 + lane;
    const float rf = (float)(p % W_);
    const float cf = (float)(p / W_);

    // This wave's 64 proto columns (32 values each) in registers; extra copies
    // across the block's 4 waves hit L1/L2, HBM fetch unchanged.
    const float* __restrict__ pp = proto + (size_t)b * NM_ * HW_ + p;
    float pr[NM_];
#pragma unroll
    for (int m = 0; m < NM_; ++m) pr[m] = pp[(size_t)m * HW_];

    const int o0 = wave * ODET_;
    const f32x4* __restrict__ sbox = (const f32x4*)det_boxes + b * NDET_ + o0;
    const int*   __restrict__ dind = det_indices + b * NDET_ + o0;

    float* __restrict__ outp =
        out + OFF_MASKS_ + ((size_t)b * NDET_ + o0) * HW_ + p;

    for (int i = 0; i < ODET_; ++i) {
        const f32x4 bx = sbox[i];                     // uniform -> s_load_dwordx4
        const float x1 = bx.x * 0.25f, y1 = bx.y * 0.25f;
        const float x2 = bx.z * 0.25f, y2 = bx.w * 0.25f;
        const bool in = (rf >= x1) & (rf < x2) & (cf >= y1) & (cf < y2);
        float v = 0.0f;
        if (__ballot(in) != 0) {
            const int idx = __builtin_amdgcn_readfirstlane(dind[i]);
            const float* __restrict__ cfp =
                x0 + ((size_t)b * N_ + idx) * XDIM_ + COEF_OFF_;
            float acc = 0.0f;
#pragma unroll
            for (int m = 0; m < NM_; ++m) acc += cfp[m] * pr[m];
            const float s = 1.0f / (1.0f + __expf(-acc));
            v = in ? s : 0.0f;
        }
        outp[(size_t)i * HW_] = v;
    }
}

extern "C" void kernel_launch(void* const* d_in, const int* in_sizes, int n_in,
                              void* d_out, int out_size, void* d_ws, size_t ws_size,
                              hipStream_t stream)
{
    const float* x0          = (const float*)d_in[0];
    const float* proto       = (const float*)d_in[1];
    const int*   num_det     = (const int*)  d_in[2];
    const float* det_boxes   = (const float*)d_in[3];
    const float* det_scores  = (const float*)d_in[4];
    const int*   det_classes = (const int*)  d_in[5];
    const int*   det_indices = (const int*)  d_in[6];
    float* out = (float*)d_out;

    dim3 grid(HW_ / 64, B_);
    mask_kernel<<<grid, 256, 0, stream>>>(
        x0, proto, num_det, det_boxes, det_scores, det_classes, det_indices, out);
}